// Round 2
// baseline (545.709 us; speedup 1.0000x reference)
//
#include <hip/hip_runtime.h>
#include <hip/hip_bf16.h>
#include <math.h>

#define D_IN 1024
#define D_HID 256
#define D_CLS 128
#define N_CLASSES 4
#define N_INST 50000

#define ROWS 64
#define NBLK ((N_INST + ROWS - 1) / ROWS)   // 782
#define NB2 64
#define CHUNK ((NBLK + NB2 - 1) / NB2)      // 13
#define NEG_BIG (-1e30f)

typedef __attribute__((ext_vector_type(8))) short bf16x8;
typedef __attribute__((ext_vector_type(4))) float f32x4;

__device__ __forceinline__ short f2bf(float x) {
    __hip_bfloat16 h = __float2bfloat16(x);
    return *reinterpret_cast<short*>(&h);
}

__device__ __forceinline__ float fast_tanh(float x) {
    float e = __expf(2.f * x);                       // v_exp_f32 (2^x via mul)
    return 1.f - 2.f * __builtin_amdgcn_rcpf(e + 1.f);
}
__device__ __forceinline__ float fast_sigmoid(float x) {
    return __builtin_amdgcn_rcpf(1.f + __expf(-x));
}

// load 8 consecutive fp32 and convert to a bf16x8 A/B fragment in registers
__device__ __forceinline__ bf16x8 load_cvt8(const float* __restrict__ p) {
    float4 a = *(const float4*)p;
    float4 b = *(const float4*)(p + 4);
    bf16x8 r;
    r[0] = f2bf(a.x); r[1] = f2bf(a.y); r[2] = f2bf(a.z); r[3] = f2bf(a.w);
    r[4] = f2bf(b.x); r[5] = f2bf(b.y); r[6] = f2bf(b.z); r[7] = f2bf(b.w);
    return r;
}

// ---------------- weight convert + transpose via LDS 64x64 tiles ----------------
// src matrices are [K][256] row-major fp32; dst are [256][K] bf16 (W^T).
__global__ void convert_weights(const float* __restrict__ w1, const float* __restrict__ wv,
                                const float* __restrict__ wa, const float* __restrict__ wb,
                                __hip_bfloat16* __restrict__ w1t, __hip_bfloat16* __restrict__ wvt,
                                __hip_bfloat16* __restrict__ wat, __hip_bfloat16* __restrict__ wbt) {
    __shared__ __hip_bfloat16 T[64][68];
    int b = blockIdx.x, tid = threadIdx.x;
    const float* src; __hip_bfloat16* dst; int K, tr, tc;
    if (b < 64) { src = w1; dst = w1t; K = D_IN; tr = b >> 2; tc = b & 3; }
    else {
        int m = (b - 64) >> 4, t = (b - 64) & 15;
        src = (m == 0) ? wv : (m == 1) ? wa : wb;
        dst = (m == 0) ? wvt : (m == 1) ? wat : wbt;
        K = D_HID; tr = t >> 2; tc = t & 3;
    }
    int k0 = tr * 64, n0 = tc * 64;
#pragma unroll
    for (int p = 0; p < 4; p++) {
        int lin = p * 256 + tid;
        int r = lin >> 4;            // local k, 0..63
        int c4 = (lin & 15) << 2;    // local n, 0..60
        float4 v = *(const float4*)(src + (size_t)(k0 + r) * D_HID + n0 + c4);
        T[c4 + 0][r] = __float2bfloat16(v.x);
        T[c4 + 1][r] = __float2bfloat16(v.y);
        T[c4 + 2][r] = __float2bfloat16(v.z);
        T[c4 + 3][r] = __float2bfloat16(v.w);
    }
    __syncthreads();
#pragma unroll
    for (int p = 0; p < 4; p++) {
        int lin = p * 256 + tid;
        int n = lin >> 4;            // local n, 0..63
        int kq = (lin & 15) << 2;    // local k, 0..60
        ushort4 o;
        o.x = *(unsigned short*)&T[n][kq + 0];
        o.y = *(unsigned short*)&T[n][kq + 1];
        o.z = *(unsigned short*)&T[n][kq + 2];
        o.w = *(unsigned short*)&T[n][kq + 3];
        *(ushort4*)(dst + (size_t)(n0 + n) * K + k0 + kq) = o;
    }
}

// 256x256 GEMM stage from LDS tile (A) x global bf16 W^T (B) -> acc
__device__ __forceinline__ void gemm256(const __hip_bfloat16 (*S)[264],
                                        const __hip_bfloat16* __restrict__ Wt,
                                        int wave, int quad, int l16, f32x4 acc[4][4]) {
    f32x4 zero = {0.f, 0.f, 0.f, 0.f};
#pragma unroll
    for (int i = 0; i < 4; i++)
#pragma unroll
        for (int j = 0; j < 4; j++) acc[i][j] = zero;
#pragma unroll
    for (int ks = 0; ks < 8; ks++) {
        bf16x8 af[4];
#pragma unroll
        for (int rt = 0; rt < 4; rt++)
            af[rt] = *(const bf16x8*)&S[rt * 16 + l16][ks * 32 + quad * 8];
#pragma unroll
        for (int ct = 0; ct < 4; ct++) {
            bf16x8 bfv = *(const bf16x8*)(Wt + (size_t)(wave * 64 + ct * 16 + l16) * D_HID + ks * 32 + quad * 8);
#pragma unroll
            for (int rt = 0; rt < 4; rt++)
                acc[rt][ct] = __builtin_amdgcn_mfma_f32_16x16x32_bf16(af[rt], bfv, acc[rt][ct], 0, 0, 0);
        }
    }
}

// ---------------- main fused kernel: 64 rows per block ----------------
__launch_bounds__(256, 2)
__global__ void mcat_main(const float* __restrict__ xp,
                          const __hip_bfloat16* __restrict__ w1t, const float* __restrict__ b1,
                          const __hip_bfloat16* __restrict__ wvt, const float* __restrict__ bv,
                          const __hip_bfloat16* __restrict__ wat, const float* __restrict__ ba,
                          const __hip_bfloat16* __restrict__ wbt, const float* __restrict__ bb,
                          const float* __restrict__ acw, const float* __restrict__ acb,
                          float* __restrict__ partials) {
    __shared__ __hip_bfloat16 Hs[ROWS][264];   // h, then g=a*b
    __shared__ __hip_bfloat16 Vs[ROWS][264];   // v (fused)
    __shared__ float Apart[4][ROWS];
    __shared__ float ExpW[ROWS];

    const int tid  = threadIdx.x;
    const int wave = tid >> 6;
    const int lane = tid & 63;
    const int quad = lane >> 4;
    const int l16  = lane & 15;
    const int row0 = blockIdx.x * ROWS;

    f32x4 acc[4][4];
    f32x4 zero = {0.f, 0.f, 0.f, 0.f};
#pragma unroll
    for (int i = 0; i < 4; i++)
#pragma unroll
        for (int j = 0; j < 4; j++) acc[i][j] = zero;

    // ---- stage 1: h = relu(X @ W1 + b1). A direct from global (no LDS, no syncthreads) ----
    const float* xbase[4];
#pragma unroll
    for (int rt = 0; rt < 4; rt++) {
        int r = row0 + rt * 16 + l16;
        if (r > N_INST - 1) r = N_INST - 1;   // clamp: valid memory, masked later
        xbase[rt] = xp + (size_t)r * D_IN + quad * 8;
    }
    const __hip_bfloat16* wbase[4];
#pragma unroll
    for (int ct = 0; ct < 4; ct++)
        wbase[ct] = w1t + (size_t)(wave * 64 + ct * 16 + l16) * D_IN + quad * 8;

    for (int ko = 0; ko < 8; ko++) {
#pragma unroll
        for (int ki = 0; ki < 4; ki++) {
            const int kc = (ko * 4 + ki) * 32;
            bf16x8 af[4];
#pragma unroll
            for (int rt = 0; rt < 4; rt++)
                af[rt] = load_cvt8(xbase[rt] + kc);
#pragma unroll
            for (int ct = 0; ct < 4; ct++) {
                bf16x8 bfv = *(const bf16x8*)(wbase[ct] + kc);
#pragma unroll
                for (int rt = 0; rt < 4; rt++)
                    acc[rt][ct] = __builtin_amdgcn_mfma_f32_16x16x32_bf16(af[rt], bfv, acc[rt][ct], 0, 0, 0);
            }
        }
        // temporal alignment only (no inter-wave data dep): keeps the 4 waves'
        // identical X reads within L1 without a vmcnt(0) drain.
        __builtin_amdgcn_s_barrier();
    }

    // epilogue: +bias, relu -> Hs (C/D map: col=lane&15, row=quad*4+reg)
#pragma unroll
    for (int ct = 0; ct < 4; ct++) {
        int col = wave * 64 + ct * 16 + l16;
        float bias = b1[col];
#pragma unroll
        for (int rt = 0; rt < 4; rt++)
#pragma unroll
            for (int r = 0; r < 4; r++) {
                int row = rt * 16 + quad * 4 + r;
                float h = acc[rt][ct][r] + bias;
                Hs[row][col] = __float2bfloat16(fmaxf(h, 0.f));
            }
    }
    __syncthreads();

    // ---- stage 2: v = h @ Wv + bv -> Vs ----
    gemm256(Hs, wvt, wave, quad, l16, acc);
#pragma unroll
    for (int ct = 0; ct < 4; ct++) {
        int col = wave * 64 + ct * 16 + l16;
        float bias = bv[col];
#pragma unroll
        for (int rt = 0; rt < 4; rt++)
#pragma unroll
            for (int r = 0; r < 4; r++) {
                int row = rt * 16 + quad * 4 + r;
                Vs[row][col] = __float2bfloat16(acc[rt][ct][r] + bias);
            }
    }
    __syncthreads();   // Hs reads done; Vs ready

    // ---- stage 3a: a = tanh(v @ Wa + ba) -> Hs ----
    gemm256(Vs, wat, wave, quad, l16, acc);
#pragma unroll
    for (int ct = 0; ct < 4; ct++) {
        int col = wave * 64 + ct * 16 + l16;
        float bias = ba[col];
#pragma unroll
        for (int rt = 0; rt < 4; rt++)
#pragma unroll
            for (int r = 0; r < 4; r++) {
                int row = rt * 16 + quad * 4 + r;
                Hs[row][col] = __float2bfloat16(fast_tanh(acc[rt][ct][r] + bias));
            }
    }
    // no barrier: stage 3b touches only its own (row,col) cells

    // ---- stage 3b: g = a * sigmoid(v @ Wb + bb) -> Hs in place ----
    gemm256(Vs, wbt, wave, quad, l16, acc);
#pragma unroll
    for (int ct = 0; ct < 4; ct++) {
        int col = wave * 64 + ct * 16 + l16;
        float bias = bb[col];
#pragma unroll
        for (int rt = 0; rt < 4; rt++)
#pragma unroll
            for (int r = 0; r < 4; r++) {
                int row = rt * 16 + quad * 4 + r;
                float bval = fast_sigmoid(acc[rt][ct][r] + bias);
                float aval = __bfloat162float(Hs[row][col]);
                Hs[row][col] = __float2bfloat16(aval * bval);
            }
    }
    __syncthreads();

    // ---- stage 4: A_n = g_n . ac_w + ac_b ----
    {
        int r = tid & 63;
        int dg = tid >> 6;
        float s = 0.f;
#pragma unroll 8
        for (int d = 0; d < 64; d++) {
            int col = dg * 64 + d;
            s += __bfloat162float(Hs[r][col]) * acw[col];
        }
        Apart[dg][r] = s;
    }
    __syncthreads();

    // ---- stage 5: block-local online-softmax partials ----
    if (tid < 64) {
        bool valid = (row0 + tid) < N_INST;
        float A = Apart[0][tid] + Apart[1][tid] + Apart[2][tid] + Apart[3][tid] + acb[0];
        if (!valid) A = NEG_BIG;
        float m = A;
#pragma unroll
        for (int off = 32; off > 0; off >>= 1) m = fmaxf(m, __shfl_xor(m, off));
        float e = valid ? __expf(A - m) : 0.f;
        ExpW[tid] = e;
        float ssum = e;
#pragma unroll
        for (int off = 32; off > 0; off >>= 1) ssum += __shfl_xor(ssum, off);
        if (tid == 0) {
            partials[(size_t)blockIdx.x * 258 + 0] = m;
            partials[(size_t)blockIdx.x * 258 + 1] = ssum;
        }
    }
    __syncthreads();
    {
        float p = 0.f;
#pragma unroll 8
        for (int n = 0; n < 64; n++)
            p += ExpW[n] * __bfloat162float(Vs[n][tid]);
        partials[(size_t)blockIdx.x * 258 + 2 + tid] = p;
    }
}

// ---------------- finalize level 1: 782 partials -> 64 ----------------
__global__ void mcat_fin_a(const float* __restrict__ p1, float* __restrict__ p2) {
    __shared__ float sm[1];
    int g = blockIdx.x, tid = threadIdx.x;
    int lo = g * CHUNK;
    int hi = lo + CHUNK; if (hi > NBLK) hi = NBLK;
    if (tid < 64) {
        float m = NEG_BIG;
        if (lo + tid < hi) m = p1[(size_t)(lo + tid) * 258];
#pragma unroll
        for (int off = 32; off > 0; off >>= 1) m = fmaxf(m, __shfl_xor(m, off));
        if (tid == 0) sm[0] = m;
    }
    __syncthreads();
    float M = sm[0];
    float p = 0.f, sacc = 0.f;
    for (int b = lo; b < hi; b++) {
        float sc = __expf(p1[(size_t)b * 258] - M);
        sacc += sc * p1[(size_t)b * 258 + 1];
        p += sc * p1[(size_t)b * 258 + 2 + tid];
    }
    if (tid == 0) {
        p2[(size_t)g * 258 + 0] = M;
        p2[(size_t)g * 258 + 1] = sacc;
    }
    p2[(size_t)g * 258 + 2 + tid] = p;
}

// ---------------- finalize level 2: 64 partials -> pooled -> classifier ----------------
__global__ void mcat_fin_b(const float* __restrict__ p2,
                           const float* __restrict__ c1w, const float* __restrict__ c1b,
                           const float* __restrict__ c2w, const float* __restrict__ c2b,
                           float* __restrict__ out) {
    __shared__ float sm[2];
    __shared__ float sc[NB2];
    __shared__ float pooled[D_HID];
    __shared__ float r1[D_CLS];
    int tid = threadIdx.x;
    if (tid < 64) {
        float m = p2[(size_t)tid * 258];
#pragma unroll
        for (int off = 32; off > 0; off >>= 1) m = fmaxf(m, __shfl_xor(m, off));
        if (tid == 0) sm[0] = m;
    }
    __syncthreads();
    float M = sm[0];
    if (tid < 64) {
        float s = __expf(p2[(size_t)tid * 258] - M);
        sc[tid] = s;
        float Ssum = s * p2[(size_t)tid * 258 + 1];
#pragma unroll
        for (int off = 32; off > 0; off >>= 1) Ssum += __shfl_xor(Ssum, off);
        if (tid == 0) sm[1] = Ssum;
    }
    __syncthreads();
    float S = sm[1];
    float p = 0.f;
#pragma unroll 8
    for (int b = 0; b < NB2; b++)
        p += sc[b] * p2[(size_t)b * 258 + 2 + tid];
    pooled[tid] = p / S;
    __syncthreads();
    if (tid < D_CLS) {
        float acc = c1b[tid];
#pragma unroll 8
        for (int d = 0; d < D_HID; d++)
            acc += pooled[d] * c1w[(size_t)d * D_CLS + tid];
        r1[tid] = fmaxf(acc, 0.f);
    }
    __syncthreads();
    if (tid < N_CLASSES) {
        float acc = c2b[tid];
#pragma unroll 8
        for (int j = 0; j < D_CLS; j++)
            acc += r1[j] * c2w[(size_t)j * N_CLASSES + tid];
        out[tid] = acc;
    }
}

extern "C" void kernel_launch(void* const* d_in, const int* in_sizes, int n_in,
                              void* d_out, int out_size, void* d_ws, size_t ws_size,
                              hipStream_t stream) {
    const float* xp  = (const float*)d_in[0];
    const float* w1  = (const float*)d_in[2];
    const float* b1  = (const float*)d_in[3];
    const float* wv  = (const float*)d_in[10];
    const float* bv  = (const float*)d_in[11];
    const float* wa  = (const float*)d_in[12];
    const float* ba  = (const float*)d_in[13];
    const float* wb  = (const float*)d_in[14];
    const float* bb  = (const float*)d_in[15];
    const float* acw = (const float*)d_in[16];
    const float* acb = (const float*)d_in[17];
    const float* c1w = (const float*)d_in[18];
    const float* c1b = (const float*)d_in[19];
    const float* c2w = (const float*)d_in[20];
    const float* c2b = (const float*)d_in[21];
    float* out = (float*)d_out;

    char* ws = (char*)d_ws;
    __hip_bfloat16* w1t = (__hip_bfloat16*)(ws);                 // 512 KB
    __hip_bfloat16* wvt = (__hip_bfloat16*)(ws + 524288);        // 128 KB
    __hip_bfloat16* wat = (__hip_bfloat16*)(ws + 655360);        // 128 KB
    __hip_bfloat16* wbt = (__hip_bfloat16*)(ws + 786432);        // 128 KB
    float* p1 = (float*)(ws + 917504);                           // 782*258*4
    float* p2 = (float*)(ws + 917504 + 807024);                  // 64*258*4

    hipLaunchKernelGGL(convert_weights, dim3(112), dim3(256), 0, stream,
                       w1, wv, wa, wb, w1t, wvt, wat, wbt);
    hipLaunchKernelGGL(mcat_main, dim3(NBLK), dim3(256), 0, stream,
                       xp, w1t, b1, wvt, bv, wat, ba, wbt, bb, acw, acb, p1);
    hipLaunchKernelGGL(mcat_fin_a, dim3(NB2), dim3(256), 0, stream, p1, p2);
    hipLaunchKernelGGL(mcat_fin_b, dim3(1), dim3(256), 0, stream,
                       p2, c1w, c1b, c2w, c2b, out);
}